// Round 5
// baseline (224.377 us; speedup 1.0000x reference)
//
#include <hip/hip_runtime.h>
#include <cmath>

typedef short bf16x8 __attribute__((ext_vector_type(8)));
typedef float f32x4 __attribute__((ext_vector_type(4)));
typedef unsigned short us8v __attribute__((ext_vector_type(8)));

#define T_DIM 1024

__device__ __forceinline__ unsigned short rtn_bf16(float f) {
    unsigned u = __float_as_uint(f);
    return (unsigned short)((u + 0x7FFFu + ((u >> 16) & 1u)) >> 16);
}
__device__ __forceinline__ float bf_to_f(unsigned short h) {
    return __uint_as_float(((unsigned)h) << 16);
}

// Truncation-based exact 3-limb split: f == bf(h1) + bf(h2) + bf(h3) + O(2^-23 |f|)
// (subtracting a truncation is exact in fp32; limbs cover >= 23 mantissa bits)
__device__ __forceinline__ void split3(float f, unsigned short& h1,
                                       unsigned short& h2, unsigned short& h3) {
    unsigned u = __float_as_uint(f);
    h1 = (unsigned short)(u >> 16);
    float r1 = f - __uint_as_float(u & 0xFFFF0000u);     // exact
    unsigned u1 = __float_as_uint(r1);
    h2 = (unsigned short)(u1 >> 16);
    float r2 = r1 - __uint_as_float(u1 & 0xFFFF0000u);   // exact
    h3 = rtn_bf16(r2);
}

// ---------------------------------------------------------------------------
// Kernel 0: split w (fp32 [k][n]) into 3 bf16 limbs, TRANSPOSED: wT[n][k].
// ---------------------------------------------------------------------------
__global__ __launch_bounds__(256) void lif_wsplit(const float* __restrict__ w,
                                                  unsigned short* __restrict__ wT1,
                                                  unsigned short* __restrict__ wT2,
                                                  unsigned short* __restrict__ wT3) {
    const int id = blockIdx.x * 256 + threadIdx.x;   // 65536 elements
    const int k = id >> 8, n = id & 255;
    unsigned short h1, h2, h3;
    split3(w[id], h1, h2, h3);
    const int o = n * 256 + k;
    wT1[o] = h1; wT2[o] = h2; wT3[o] = h3;
}

// ---------------------------------------------------------------------------
// Kernel 1: bf16-MFMA GEMM, 3-limb split of A (in-kernel) and W (precomputed).
// 6 MFMA products: a1w1,a1w2,a2w1,a2w2,a1w3,a3w1 (drops ~2^-24-rel terms).
// Block 128m x 128n, BK=64, 4 waves each 64x64. grid (512, 2).
// LDS: LDA=64 (no pad) with XOR chunk swizzle (chunk ^= row&7):
//   16B stores/reads land 8 lanes per 4-bank group = minimum depth, 0 conflicts.
// ---------------------------------------------------------------------------
__global__ __launch_bounds__(256) void lif_gemm_mfma(const float* __restrict__ in,
                                                     const unsigned short* __restrict__ wT1,
                                                     const unsigned short* __restrict__ wT2,
                                                     const unsigned short* __restrict__ wT3,
                                                     float* __restrict__ xbuf) {
    __shared__ unsigned short As[3][128 * 64];   // 3 limb tiles, 48 KiB

    const int tid  = threadIdx.x;
    const int bm   = blockIdx.x;           // 0..511 (128-row tiles)
    const int bn   = blockIdx.y;           // 0..1   (128-col tiles)
    const int wave = tid >> 6;
    const int lane = tid & 63;
    const int l15  = lane & 15;
    const int quad = lane >> 4;
    const int wm   = (wave >> 1) * 64;     // wave's 64x64 sub-tile
    const int wn   = (wave & 1) * 64;

    f32x4 acc[4][4];
    #pragma unroll
    for (int i = 0; i < 4; ++i)
        #pragma unroll
        for (int j = 0; j < 4; ++j) acc[i][j] = (f32x4){0.f, 0.f, 0.f, 0.f};

    const int r  = tid >> 1;               // staging row 0..127
    const int hf = tid & 1;                // staging k-half (32 floats)
    const int rx = r & 7;                  // XOR swizzle key
    const float* arow = in + (size_t)(bm * 128 + r) * 256 + hf * 32;

    for (int kt = 0; kt < 4; ++kt) {
        const int k0 = kt * 64;
        // prefetch this chunk's A data to registers before the barrier
        float4 av[8];
        #pragma unroll
        for (int j = 0; j < 8; ++j)
            av[j] = *(const float4*)(arow + k0 + j * 4);

        __syncthreads();                   // previous chunk fully consumed
        #pragma unroll
        for (int j2 = 0; j2 < 4; ++j2) {
            const float fv[8] = {av[2*j2].x, av[2*j2].y, av[2*j2].z, av[2*j2].w,
                                 av[2*j2+1].x, av[2*j2+1].y, av[2*j2+1].z, av[2*j2+1].w};
            us8v o1, o2, o3;
            #pragma unroll
            for (int i = 0; i < 8; ++i) {
                unsigned short h1, h2, h3;
                split3(fv[i], h1, h2, h3);
                o1[i] = h1; o2[i] = h2; o3[i] = h3;
            }
            const int cp = ((hf * 4 + j2) ^ rx) * 8;      // swizzled chunk offset
            *(us8v*)&As[0][r * 64 + cp] = o1;
            *(us8v*)&As[1][r * 64 + cp] = o2;
            *(us8v*)&As[2][r * 64 + cp] = o3;
        }
        __syncthreads();

        #pragma unroll
        for (int ks = 0; ks < 2; ++ks) {
            // A fragments: A[m = l15][k = quad*8 + j], swizzled chunk
            bf16x8 af[3][4];
            const int ko = ((ks * 4 + quad) ^ (l15 & 7)) * 8;
            #pragma unroll
            for (int mt = 0; mt < 4; ++mt) {
                const int ro = (wm + mt * 16 + l15) * 64 + ko;
                af[0][mt] = *(const bf16x8*)&As[0][ro];
                af[1][mt] = *(const bf16x8*)&As[1][ro];
                af[2][mt] = *(const bf16x8*)&As[2][ro];
            }
            #pragma unroll
            for (int nt = 0; nt < 4; ++nt) {
                // B fragments from global wT (L2-resident): B[k=quad*8+j][n=l15]
                const int ncol = bn * 128 + wn + nt * 16 + l15;
                const size_t wo = (size_t)ncol * 256 + k0 + ks * 32 + quad * 8;
                const bf16x8 b1 = *(const bf16x8*)(wT1 + wo);
                const bf16x8 b2 = *(const bf16x8*)(wT2 + wo);
                const bf16x8 b3 = *(const bf16x8*)(wT3 + wo);
                #pragma unroll
                for (int mt = 0; mt < 4; ++mt) {
                    f32x4 a = acc[mt][nt];
                    a = __builtin_amdgcn_mfma_f32_16x16x32_bf16(af[0][mt], b1, a, 0, 0, 0);
                    a = __builtin_amdgcn_mfma_f32_16x16x32_bf16(af[0][mt], b2, a, 0, 0, 0);
                    a = __builtin_amdgcn_mfma_f32_16x16x32_bf16(af[1][mt], b1, a, 0, 0, 0);
                    a = __builtin_amdgcn_mfma_f32_16x16x32_bf16(af[1][mt], b2, a, 0, 0, 0);
                    a = __builtin_amdgcn_mfma_f32_16x16x32_bf16(af[0][mt], b3, a, 0, 0, 0);
                    a = __builtin_amdgcn_mfma_f32_16x16x32_bf16(af[2][mt], b1, a, 0, 0, 0);
                    acc[mt][nt] = a;
                }
            }
        }
    }

    // epilogue: C/D layout col=lane&15, row=(lane>>4)*4+reg (verified m89)
    #pragma unroll
    for (int mt = 0; mt < 4; ++mt) {
        #pragma unroll
        for (int nt = 0; nt < 4; ++nt) {
            const int C = bn * 128 + wn + nt * 16 + l15;
            const int Rb = bm * 128 + wm + mt * 16 + quad * 4;
            #pragma unroll
            for (int reg = 0; reg < 4; ++reg)
                xbuf[(size_t)(Rb + reg) * 256 + C] = acc[mt][nt][reg];
        }
    }
}

// ---------------------------------------------------------------------------
// Kernel 2: LIF scan, streaming. 256 blocks x 64 threads (1 wave each):
// block = (b, o-group of 64). x staged through a 16 KiB LDS tile (transpose
// medium); chunk c+1's 16 float4 loads are in flight while chunk c scans.
// ---------------------------------------------------------------------------
__global__ __launch_bounds__(64) void lif_scan(const float* __restrict__ xbuf,
                                               float* __restrict__ U,
                                               double dcy_syn, double dcy_mem,
                                               double scl_mem) {
    __shared__ float xs[64][64];    // [t-local][o-local]

    const int b    = blockIdx.x >> 2;
    const int og   = blockIdx.x & 3;
    const int lane = threadIdx.x;

    const float* src = xbuf + (size_t)b * T_DIM * 256 + og * 64;
    float* up = U + (size_t)b * T_DIM * 256 + og * 64 + lane;

    up[0] = 0.0f;                   // U[b][0][o] = initial state
    double syn = 0.0, mem = 0.0;

    float4 pre[16];
    #pragma unroll
    for (int i = 0; i < 16; ++i) {  // chunk 0
        const int f = i * 64 + lane;
        pre[i] = *(const float4*)(src + (size_t)(f >> 4) * 256 + (f & 15) * 4);
    }

    for (int c = 0; c < 16; ++c) {
        __syncthreads();
        #pragma unroll
        for (int i = 0; i < 16; ++i) {
            const int f = i * 64 + lane;
            *(float4*)&xs[f >> 4][(f & 15) * 4] = pre[i];
        }
        __syncthreads();
        if (c < 15) {               // prefetch next chunk; in flight during scan
            const float* nsrc = src + (size_t)(c + 1) * 64 * 256;
            #pragma unroll
            for (int i = 0; i < 16; ++i) {
                const int f = i * 64 + lane;
                pre[i] = *(const float4*)(nsrc + (size_t)(f >> 4) * 256 + (f & 15) * 4);
            }
        }
        const int tbase = c * 64;
        #pragma unroll 8
        for (int j = 0; j < 64; ++j) {
            const double x = (double)xs[j][lane];
            double nm = dcy_mem * mem + scl_mem * syn;
            if (mem - 1.0 > 0.0) nm = 0.0;
            syn = dcy_syn * syn + x;
            mem = nm;
            const int t = tbase + j;
            if (t < T_DIM - 1)
                up[(size_t)(t + 1) * 256] = (float)mem;
        }
    }
}

extern "C" void kernel_launch(void* const* d_in, const int* in_sizes, int n_in,
                              void* d_out, int out_size, void* d_ws, size_t ws_size,
                              hipStream_t stream) {
    const float* in = (const float*)d_in[0];   // fp32 [64][1024][256]
    const float* w  = (const float*)d_in[1];   // fp32 [256][256]
    float* U = (float*)d_out;                  // fp32 [64][1024][256]

    const double dcy_mem = exp(-0.001 / (0.01  + 1e-16));
    const double dcy_syn = exp(-0.001 / (0.005 + 1e-16));
    const double scl_mem = 1.0 - dcy_mem;

    // ws layout: wT1|wT2|wT3 (3 x 128 KiB bf16) | xbuf (64 MiB fp32)
    char* ws = (char*)d_ws;
    unsigned short* wT1 = (unsigned short*)ws;
    unsigned short* wT2 = (unsigned short*)(ws + 131072);
    unsigned short* wT3 = (unsigned short*)(ws + 262144);
    float* xbuf = (float*)(ws + 524288);

    lif_wsplit<<<dim3(256), dim3(256), 0, stream>>>(w, wT1, wT2, wT3);
    lif_gemm_mfma<<<dim3(512, 2), dim3(256), 0, stream>>>(in, wT1, wT2, wT3, xbuf);
    lif_scan<<<dim3(256), dim3(64), 0, stream>>>(xbuf, U, dcy_syn, dcy_mem, scl_mem);
}